// Round 21
// baseline (211.671 us; speedup 1.0000x reference)
//
#include <hip/hip_runtime.h>
#include <hip/hip_bf16.h>

typedef __attribute__((ext_vector_type(8))) short short8;
typedef __attribute__((ext_vector_type(4))) short short4v;
typedef __attribute__((ext_vector_type(4))) float f32x4;

static __device__ __forceinline__ unsigned short f2bf(float f) {
  unsigned int u = __float_as_uint(f);
  u += 0x7fffu + ((u >> 16) & 1u);
  return (unsigned short)(u >> 16);
}

// HW packed f32x2 -> bf16x2 (gfx950 v_cvt_pk_bf16_f32; no builtin exists)
static __device__ __forceinline__ unsigned cvtpk(float a, float b) {
  unsigned r;
  asm("v_cvt_pk_bf16_f32 %0, %1, %2" : "=v"(r) : "v"(a), "v"(b));
  return r;
}

static __device__ __forceinline__ void gload_lds16(const unsigned short* g,
                                                   unsigned short* l) {
  __builtin_amdgcn_global_load_lds((const __attribute__((address_space(1))) void*)g,
                                   (__attribute__((address_space(3))) void*)l, 16, 0, 0);
}

// 4 weights [K,N] fp32 -> [N,K] bf16 in one launch
__global__ void wtrans4_kernel(const float* __restrict__ W0, const float* __restrict__ W1,
                               const float* __restrict__ W2, const float* __restrict__ W3,
                               unsigned short* __restrict__ T0, unsigned short* __restrict__ T1,
                               unsigned short* __restrict__ T2, unsigned short* __restrict__ T3) {
  const float* W = blockIdx.z == 0 ? W0 : (blockIdx.z == 1 ? W1 : (blockIdx.z == 2 ? W2 : W3));
  unsigned short* Wt = blockIdx.z == 0 ? T0 : (blockIdx.z == 1 ? T1 : (blockIdx.z == 2 ? T2 : T3));
  __shared__ float t[32][33];
  int n0 = blockIdx.x * 32, k0 = blockIdx.y * 32;
#pragma unroll
  for (int j = 0; j < 4; ++j)
    t[threadIdx.y + j * 8][threadIdx.x] =
        W[(size_t)(k0 + threadIdx.y + j * 8) * 1024 + n0 + threadIdx.x];
  __syncthreads();
#pragma unroll
  for (int j = 0; j < 4; ++j)
    Wt[(size_t)(n0 + threadIdx.y + j * 8) * 1024 + k0 + threadIdx.x] =
        f2bf(t[threadIdx.x][threadIdx.y + j * 8]);
}

// energy -> Mf (float 0/1) and Mbf (bf16 0/1)
__global__ void mask_kernel(const float* __restrict__ e, float* __restrict__ Mf,
                            unsigned short* __restrict__ Mbf, int n) {
  int i = blockIdx.x * blockDim.x + threadIdx.x;
  if (i < n) {
    float m = (fabsf(e[i]) > 0.1f) ? 1.0f : 0.0f;
    Mf[i] = m;
    Mbf[i] = f2bf(m);
  }
}

// ---------------- Q/K GEMM (v9 pipeline, SWAP path, single plane per launch) --------
// out = (X@Wt^T + bias)*scale -> bf16 [B,H,2048,64]. Grid (64,8), 256 thr.
__global__ __launch_bounds__(256, 4) void gemm_qk_kernel(
    const float* __restrict__ X32, const unsigned short* __restrict__ Wt,
    const float* __restrict__ bias, unsigned short* __restrict__ out, float scale) {
  const int K = 1024;
  __shared__ unsigned short Al[2][128 * 32];
  __shared__ unsigned short Bl[3][128 * 32];
  const int m0 = blockIdx.x * 128, n0 = blockIdx.y * 128;
  const int tid = threadIdx.x, lane = tid & 63, wid = tid >> 6;
  const int wr = wid >> 1, wc = wid & 1;
  const int g = lane >> 4, lr = lane & 15;
  const f32x4 fz = {0.f, 0.f, 0.f, 0.f};
  f32x4 acc[4][4];
#pragma unroll
  for (int i = 0; i < 4; i++)
#pragma unroll
    for (int j = 0; j < 4; j++) acc[i][j] = fz;

  const int sr0 = tid >> 2;
  const int sr1 = (256 + tid) >> 2;
  const int chk = ((tid & 3) ^ ((tid >> 3) & 3)) * 8;
  const int offr = (g ^ ((lr >> 1) & 3)) * 8;
  const float* pA0 = X32 + (size_t)(m0 + sr0) * K + chk;
  const float* pA1 = X32 + (size_t)(m0 + sr1) * K + chk;

  float4 ra0, ra1, rb0, rb1;

  auto stageB = [&](int kk, int bi) {
    gload_lds16(Wt + (size_t)(n0 + sr0) * K + kk + chk, &Bl[bi][wid * 512]);
    gload_lds16(Wt + (size_t)(n0 + sr1) * K + kk + chk, &Bl[bi][2048 + wid * 512]);
  };
  auto loadA = [&](int kk) {
    ra0 = *(const float4*)(pA0 + kk);
    ra1 = *(const float4*)(pA0 + kk + 4);
    rb0 = *(const float4*)(pA1 + kk);
    rb1 = *(const float4*)(pA1 + kk + 4);
  };
  auto writeA = [&](int ai) {
    uint4 s0, s1;
    s0.x = cvtpk(ra0.x, ra0.y); s0.y = cvtpk(ra0.z, ra0.w);
    s0.z = cvtpk(ra1.x, ra1.y); s0.w = cvtpk(ra1.z, ra1.w);
    s1.x = cvtpk(rb0.x, rb0.y); s1.y = cvtpk(rb0.z, rb0.w);
    s1.z = cvtpk(rb1.x, rb1.y); s1.w = cvtpk(rb1.z, rb1.w);
    *(uint4*)(&Al[ai][tid * 8]) = s0;
    *(uint4*)(&Al[ai][2048 + tid * 8]) = s1;
  };

  loadA(0);
  stageB(0, 0);
  writeA(0);
  stageB(32, 1);
  loadA(32);
  __syncthreads();

  int ab = 0;
  int b0 = 0, b1 = 1, b2 = 2;
  for (int t = 0; t < 32; ++t) {
    const int k0 = t * 32;
    if (t < 31) writeA(ab ^ 1);
    if (t < 30) {
      stageB(k0 + 64, b2);
      loadA(k0 + 64);
    }
    short8 a[4], b[4];
#pragma unroll
    for (int i = 0; i < 4; i++)
      a[i] = *(const short8*)(&Al[ab][(wr * 64 + i * 16 + lr) * 32 + offr]);
#pragma unroll
    for (int i = 0; i < 4; i++)
      b[i] = *(const short8*)(&Bl[b0][(wc * 64 + i * 16 + lr) * 32 + offr]);
#pragma unroll
    for (int i = 0; i < 4; i++)
#pragma unroll
      for (int j = 0; j < 4; j++)
        acc[i][j] = __builtin_amdgcn_mfma_f32_16x16x32_bf16(b[j], a[i], acc[i][j], 0, 0, 0);
    asm volatile("s_waitcnt lgkmcnt(0)" ::: "memory");
    __builtin_amdgcn_s_barrier();
    __builtin_amdgcn_sched_barrier(0);
    ab ^= 1;
    int tmp = b0; b0 = b1; b1 = b2; b2 = tmp;
  }

#pragma unroll
  for (int i = 0; i < 4; i++) {
    const int mrow = m0 + wr * 64 + i * 16 + lr;
    const int b_ = mrow >> 11, l = mrow & 2047;
#pragma unroll
    for (int j = 0; j < 4; j++) {
      const int ncol0 = n0 + wc * 64 + j * 16 + g * 4;
      const int h = ncol0 >> 6, dh = ncol0 & 63;
      const f32x4 bb = *(const f32x4*)(bias + ncol0);
      uint2 st;
      st.x = cvtpk((acc[i][j][0] + bb[0]) * scale, (acc[i][j][1] + bb[1]) * scale);
      st.y = cvtpk((acc[i][j][2] + bb[2]) * scale, (acc[i][j][3] + bb[3]) * scale);
      *(uint2*)(out + ((size_t)(b_ * 16 + h) * 2048 + l) * 64 + dh) = st;
    }
  }
}

// ---------------- V GEMM (v9 pipeline, natural path) ----------------
// Vt = (v_x@Wv^T + bv)*Mf -> bf16 [B,H,64,2048]. Grid (64,8), 256 thr.
__global__ __launch_bounds__(256, 4) void gemm_v_kernel(
    const float* __restrict__ X32, const unsigned short* __restrict__ Wt,
    const float* __restrict__ bias, unsigned short* __restrict__ Vt,
    const float* __restrict__ Mf) {
  const int K = 1024;
  __shared__ unsigned short Al[2][128 * 32];
  __shared__ unsigned short Bl[3][128 * 32];
  const int m0 = blockIdx.x * 128, n0 = blockIdx.y * 128;
  const int tid = threadIdx.x, lane = tid & 63, wid = tid >> 6;
  const int wr = wid >> 1, wc = wid & 1;
  const int g = lane >> 4, lr = lane & 15;
  const f32x4 fz = {0.f, 0.f, 0.f, 0.f};
  f32x4 acc[4][4];
#pragma unroll
  for (int i = 0; i < 4; i++)
#pragma unroll
    for (int j = 0; j < 4; j++) acc[i][j] = fz;

  const int sr0 = tid >> 2;
  const int sr1 = (256 + tid) >> 2;
  const int chk = ((tid & 3) ^ ((tid >> 3) & 3)) * 8;
  const int offr = (g ^ ((lr >> 1) & 3)) * 8;
  const float* pA0 = X32 + (size_t)(m0 + sr0) * K + chk;
  const float* pA1 = X32 + (size_t)(m0 + sr1) * K + chk;

  float4 ra0, ra1, rb0, rb1;

  auto stageB = [&](int kk, int bi) {
    gload_lds16(Wt + (size_t)(n0 + sr0) * K + kk + chk, &Bl[bi][wid * 512]);
    gload_lds16(Wt + (size_t)(n0 + sr1) * K + kk + chk, &Bl[bi][2048 + wid * 512]);
  };
  auto loadA = [&](int kk) {
    ra0 = *(const float4*)(pA0 + kk);
    ra1 = *(const float4*)(pA0 + kk + 4);
    rb0 = *(const float4*)(pA1 + kk);
    rb1 = *(const float4*)(pA1 + kk + 4);
  };
  auto writeA = [&](int ai) {
    uint4 s0, s1;
    s0.x = cvtpk(ra0.x, ra0.y); s0.y = cvtpk(ra0.z, ra0.w);
    s0.z = cvtpk(ra1.x, ra1.y); s0.w = cvtpk(ra1.z, ra1.w);
    s1.x = cvtpk(rb0.x, rb0.y); s1.y = cvtpk(rb0.z, rb0.w);
    s1.z = cvtpk(rb1.x, rb1.y); s1.w = cvtpk(rb1.z, rb1.w);
    *(uint4*)(&Al[ai][tid * 8]) = s0;
    *(uint4*)(&Al[ai][2048 + tid * 8]) = s1;
  };

  loadA(0);
  stageB(0, 0);
  writeA(0);
  stageB(32, 1);
  loadA(32);
  __syncthreads();

  int ab = 0;
  int b0 = 0, b1 = 1, b2 = 2;
  for (int t = 0; t < 32; ++t) {
    const int k0 = t * 32;
    if (t < 31) writeA(ab ^ 1);
    if (t < 30) {
      stageB(k0 + 64, b2);
      loadA(k0 + 64);
    }
    short8 a[4], b[4];
#pragma unroll
    for (int i = 0; i < 4; i++)
      a[i] = *(const short8*)(&Al[ab][(wr * 64 + i * 16 + lr) * 32 + offr]);
#pragma unroll
    for (int i = 0; i < 4; i++)
      b[i] = *(const short8*)(&Bl[b0][(wc * 64 + i * 16 + lr) * 32 + offr]);
#pragma unroll
    for (int i = 0; i < 4; i++)
#pragma unroll
      for (int j = 0; j < 4; j++)
        acc[i][j] = __builtin_amdgcn_mfma_f32_16x16x32_bf16(a[i], b[j], acc[i][j], 0, 0, 0);
    asm volatile("s_waitcnt lgkmcnt(0)" ::: "memory");
    __builtin_amdgcn_s_barrier();
    __builtin_amdgcn_sched_barrier(0);
    ab ^= 1;
    int tmp = b0; b0 = b1; b1 = b2; b2 = tmp;
  }

#pragma unroll
  for (int i = 0; i < 4; i++) {
    const int mrow0 = m0 + wr * 64 + i * 16 + g * 4;
    const int b_ = mrow0 >> 11, s = mrow0 & 2047;
    const f32x4 mf = *(const f32x4*)(Mf + mrow0);
#pragma unroll
    for (int j = 0; j < 4; j++) {
      const int ncol = n0 + wc * 64 + j * 16 + lr;
      const float bv_ = bias[ncol];
      const int h = ncol >> 6, d = ncol & 63;
      uint2 pk;
      pk.x = cvtpk((acc[i][j][0] + bv_) * mf[0], (acc[i][j][1] + bv_) * mf[1]);
      pk.y = cvtpk((acc[i][j][2] + bv_) * mf[2], (acc[i][j][3] + bv_) * mf[3]);
      *(uint2*)(Vt + ((size_t)(b_ * 16 + h) * 64 + d) * 2048 + s) = pk;
    }
  }
}

// ---------------- output GEMM v5 (fp32 out, swapped, swizzled) ----------------
__global__ __launch_bounds__(256, 4) void gemm_out_kernel(
    const unsigned short* __restrict__ X, const unsigned short* __restrict__ Wt,
    const float* __restrict__ bias, float* __restrict__ out) {
  const int K = 1024;
  __shared__ unsigned short Al[2][128 * 32];
  __shared__ unsigned short Bl[2][128 * 32];
  const int m0 = blockIdx.x * 128, n0 = blockIdx.y * 128;
  const int tid = threadIdx.x, lane = tid & 63, wid = tid >> 6;
  const int wr = wid >> 1, wc = wid & 1;
  const int g = lane >> 4, lr = lane & 15;
  const f32x4 fz = {0.f, 0.f, 0.f, 0.f};
  f32x4 acc[4][4];
#pragma unroll
  for (int i = 0; i < 4; i++)
#pragma unroll
    for (int j = 0; j < 4; j++) acc[i][j] = fz;

  const int sr0 = tid >> 2;
  const int sr1 = (256 + tid) >> 2;
  const int sc0s = ((tid & 3) ^ ((tid >> 3) & 3)) * 8;
  const int offr = (g ^ ((lr >> 1) & 3)) * 8;

  auto stage = [&](int kk, int buf) {
    gload_lds16(X + (size_t)(m0 + sr0) * K + kk + sc0s, &Al[buf][wid * 512]);
    gload_lds16(X + (size_t)(m0 + sr1) * K + kk + sc0s, &Al[buf][2048 + wid * 512]);
    gload_lds16(Wt + (size_t)(n0 + sr0) * K + kk + sc0s, &Bl[buf][wid * 512]);
    gload_lds16(Wt + (size_t)(n0 + sr1) * K + kk + sc0s, &Bl[buf][2048 + wid * 512]);
  };

  stage(0, 0);
  __syncthreads();

  int buf = 0;
  for (int k0 = 0; k0 < K; k0 += 32) {
    if (k0 < K - 32) stage(k0 + 32, buf ^ 1);
    short8 a[4], b[4];
#pragma unroll
    for (int i = 0; i < 4; i++)
      a[i] = *(const short8*)(&Al[buf][(wr * 64 + i * 16 + lr) * 32 + offr]);
#pragma unroll
    for (int i = 0; i < 4; i++)
      b[i] = *(const short8*)(&Bl[buf][(wc * 64 + i * 16 + lr) * 32 + offr]);
#pragma unroll
    for (int i = 0; i < 4; i++)
#pragma unroll
      for (int j = 0; j < 4; j++)
        acc[i][j] = __builtin_amdgcn_mfma_f32_16x16x32_bf16(b[j], a[i], acc[i][j], 0, 0, 0);
    __syncthreads();
    buf ^= 1;
  }

#pragma unroll
  for (int i = 0; i < 4; i++) {
    const int mrow = m0 + wr * 64 + i * 16 + lr;
#pragma unroll
    for (int j = 0; j < 4; j++) {
      const int ncol0 = n0 + wc * 64 + j * 16 + g * 4;
      const f32x4 bb = *(const f32x4*)(bias + ncol0);
      f32x4 st = acc[i][j] + bb;
      *(f32x4*)(out + (size_t)mrow * 1024 + ncol0) = st;
    }
  }
}

// ---------------- flash attention v12 (unchanged) ----------------
__global__ __launch_bounds__(256, 4) void attn_kernel(
    const unsigned short* __restrict__ Qh, const unsigned short* __restrict__ Kh,
    const unsigned short* __restrict__ Vt, const unsigned short* __restrict__ Mbf,
    unsigned short* __restrict__ AO) {
  const int S = 2048;
  __shared__ unsigned short Lds[2][8192];
  int bx = blockIdx.x;
  int lid = (bx & 7) * 128 + (bx >> 3);
  const int bh = lid >> 4, qbb = lid & 15;
  const int b_ = bh >> 4, h = bh & 15;
  const unsigned short* Qp = Qh + (size_t)bh * S * 64;
  const unsigned short* Kp = Kh + (size_t)bh * S * 64;
  const unsigned short* Vp = Vt + (size_t)bh * 64 * S;
  const unsigned short* Mp = Mbf + b_ * S;
  const int tid = threadIdx.x, lane = tid & 63, wid = tid >> 6;
  const int g = lane >> 4, lr = lane & 15;
  const int qbase = qbb * 128 + wid * 32;
  const f32x4 fz = {0.f, 0.f, 0.f, 0.f};

  const int srow = (lane >> 3);
  const int schk = (lane & 7) ^ srow;
  const int kr0 = wid * 16 + srow, kr1 = wid * 16 + 8 + srow;
  const int pir0 = (kr0 & 32) | ((kr0 & 12) << 1) | ((kr0 & 16) >> 2) | (kr0 & 3);
  const int pir1 = (kr1 & 32) | ((kr1 & 12) << 1) | ((kr1 & 16) >> 2) | (kr1 & 3);
  const unsigned short* gK0 = Kp + (size_t)pir0 * 64 + schk * 8;
  const unsigned short* gK1 = Kp + (size_t)pir1 * 64 + schk * 8;
  const unsigned short* gV0 = Vp + (size_t)kr0 * S + schk * 8;
  const unsigned short* gV1 = Vp + (size_t)kr1 * S + schk * 8;

  const int s7 = lr & 7;
  const int off0 = ((g ^ s7) * 8);
  const int off1 = (((4 + g) ^ s7) * 8);

  short8 qf[2][2];
#pragma unroll
  for (int qt = 0; qt < 2; qt++)
#pragma unroll
    for (int kh = 0; kh < 2; kh++)
      qf[qt][kh] = *(const short8*)(Qp + (size_t)(qbase + qt * 16 + lr) * 64 + kh * 32 + g * 8);

  f32x4 o[2][4];
  f32x4 psA[2];
#pragma unroll
  for (int qt = 0; qt < 2; qt++) {
    psA[qt] = fz;
#pragma unroll
    for (int t = 0; t < 4; t++) o[qt][t] = fz;
  }

  auto stage = [&](int s0, int buf) {
    gload_lds16(gK0 + (size_t)s0 * 64, &Lds[buf][wid * 1024]);
    gload_lds16(gK1 + (size_t)s0 * 64, &Lds[buf][wid * 1024 + 512]);
    gload_lds16(gV0 + s0, &Lds[buf][4096 + wid * 1024]);
    gload_lds16(gV1 + s0, &Lds[buf][4096 + wid * 1024 + 512]);
  };

  stage(0, 0);
  __syncthreads();

  int cur = 0;
  for (int t = 0; t < 32; ++t) {
    const int s0 = t * 64;
    if (t < 31) stage(s0 + 64, cur ^ 1);
    const unsigned short* Kb = &Lds[cur][lr * 64];
    const unsigned short* Vb = &Lds[cur][4096 + lr * 64];

    short8 kf[4][2];
#pragma unroll
    for (int st = 0; st < 4; st++) {
      kf[st][0] = *(const short8*)(Kb + st * 1024 + off0);
      kf[st][1] = *(const short8*)(Kb + st * 1024 + off1);
    }
    short8 mk0 = *(const short8*)(Mp + s0 + g * 8);
    short8 mk1 = *(const short8*)(Mp + s0 + 32 + g * 8);

    union { unsigned u[8]; short8 s8[2]; } pk[2];
    __builtin_amdgcn_s_setprio(1);
#pragma unroll
    for (int qt = 0; qt < 2; qt++) {
#pragma unroll
      for (int st = 0; st < 4; st++) {
        f32x4 a0 = __builtin_amdgcn_mfma_f32_16x16x32_bf16(kf[st][0], qf[qt][0], fz, 0, 0, 0);
        f32x4 s = __builtin_amdgcn_mfma_f32_16x16x32_bf16(kf[st][1], qf[qt][1], a0, 0, 0, 0);
        f32x4 p;
#pragma unroll
        for (int e = 0; e < 4; e++) p[e] = __builtin_amdgcn_exp2f(s[e]);
        pk[qt].u[st * 2] = cvtpk(p[0], p[1]);
        pk[qt].u[st * 2 + 1] = cvtpk(p[2], p[3]);
      }
      psA[qt] = __builtin_amdgcn_mfma_f32_16x16x32_bf16(mk0, pk[qt].s8[0], psA[qt], 0, 0, 0);
      psA[qt] = __builtin_amdgcn_mfma_f32_16x16x32_bf16(mk1, pk[qt].s8[1], psA[qt], 0, 0, 0);
    }
    __builtin_amdgcn_s_setprio(0);

#pragma unroll
    for (int tt = 0; tt < 4; tt++) {
      short8 v0 = *(const short8*)(Vb + tt * 1024 + off0);
      short8 v1 = *(const short8*)(Vb + tt * 1024 + off1);
      __builtin_amdgcn_s_setprio(1);
#pragma unroll
      for (int qt = 0; qt < 2; qt++) {
        o[qt][tt] = __builtin_amdgcn_mfma_f32_16x16x32_bf16(v0, pk[qt].s8[0], o[qt][tt], 0, 0, 0);
        o[qt][tt] = __builtin_amdgcn_mfma_f32_16x16x32_bf16(v1, pk[qt].s8[1], o[qt][tt], 0, 0, 0);
      }
      __builtin_amdgcn_s_setprio(0);
    }
    __syncthreads();
    cur ^= 1;
  }

#pragma unroll
  for (int qt = 0; qt < 2; qt++) {
    float l = psA[qt][0];
    float inv = l > 0.f ? 1.f / l : 0.f;
    size_t row = (size_t)b_ * 2048 + qbase + qt * 16 + lr;
#pragma unroll
    for (int tt = 0; tt < 4; tt++) {
      uint2 wv;
      wv.x = cvtpk(o[qt][tt][0] * inv, o[qt][tt][1] * inv);
      wv.y = cvtpk(o[qt][tt][2] * inv, o[qt][tt][3] * inv);
      *(uint2*)(AO + row * 1024 + h * 64 + tt * 16 + g * 4) = wv;
    }
  }
}

// ---------------- launch ----------------
extern "C" void kernel_launch(void* const* d_in, const int* in_sizes, int n_in,
                              void* d_out, int out_size, void* d_ws, size_t ws_size,
                              hipStream_t stream) {
  const float* q_x = (const float*)d_in[0];
  const float* k_x = (const float*)d_in[1];
  const float* v_x = (const float*)d_in[2];
  const float* energy = (const float*)d_in[3];
  const float* Wq = (const float*)d_in[4];
  const float* bq = (const float*)d_in[5];
  const float* Wk = (const float*)d_in[6];
  const float* bk = (const float*)d_in[7];
  const float* Wv = (const float*)d_in[8];
  const float* bv = (const float*)d_in[9];
  const float* Wo = (const float*)d_in[10];
  const float* bo = (const float*)d_in[11];

  char* w = (char*)d_ws;
  auto take = [&](size_t bytes) {
    char* p = w;
    w += (bytes + 255) & ~(size_t)255;
    return p;
  };
  const size_t XB = (size_t)8192 * 1024 * 2;
  unsigned short* Wtq = (unsigned short*)take((size_t)1024 * 1024 * 2);
  unsigned short* Wtk = (unsigned short*)take((size_t)1024 * 1024 * 2);
  unsigned short* Wtv = (unsigned short*)take((size_t)1024 * 1024 * 2);
  unsigned short* Wto = (unsigned short*)take((size_t)1024 * 1024 * 2);
  float* Mf = (float*)take((size_t)8192 * 4);
  unsigned short* Mbf = (unsigned short*)take((size_t)8192 * 2);
  unsigned short* Qh = (unsigned short*)take(XB);
  unsigned short* Kh = (unsigned short*)take(XB);
  unsigned short* Vt = (unsigned short*)take(XB);
  unsigned short* AO = (unsigned short*)take(XB);

  const float c2 = 0.18033688011f;  // log2(e)/sqrt(64)
  wtrans4_kernel<<<dim3(32, 32, 4), dim3(32, 8), 0, stream>>>(Wq, Wk, Wv, Wo, Wtq, Wtk, Wtv, Wto);
  mask_kernel<<<32, 256, 0, stream>>>(energy, Mf, Mbf, 8192);

  gemm_qk_kernel<<<dim3(64, 8), 256, 0, stream>>>(q_x, Wtq, bq, Qh, c2);
  gemm_qk_kernel<<<dim3(64, 8), 256, 0, stream>>>(k_x, Wtk, bk, Kh, 1.0f);
  gemm_v_kernel<<<dim3(64, 8), 256, 0, stream>>>(v_x, Wtv, bv, Vt, Mf);
  attn_kernel<<<1024, 256, 0, stream>>>(Qh, Kh, Vt, Mbf, AO);
  gemm_out_kernel<<<dim3(64, 8), 256, 0, stream>>>(AO, Wto, bo, (float*)d_out);
}

// Round 22
// 194.605 us; speedup vs baseline: 1.0877x; 1.0877x over previous
//
#include <hip/hip_runtime.h>
#include <hip/hip_bf16.h>

typedef __attribute__((ext_vector_type(8))) short short8;
typedef __attribute__((ext_vector_type(4))) short short4v;
typedef __attribute__((ext_vector_type(4))) float f32x4;

static __device__ __forceinline__ unsigned short f2bf(float f) {
  unsigned int u = __float_as_uint(f);
  u += 0x7fffu + ((u >> 16) & 1u);
  return (unsigned short)(u >> 16);
}

// HW packed f32x2 -> bf16x2 (gfx950 v_cvt_pk_bf16_f32; no builtin exists)
static __device__ __forceinline__ unsigned cvtpk(float a, float b) {
  unsigned r;
  asm("v_cvt_pk_bf16_f32 %0, %1, %2" : "=v"(r) : "v"(a), "v"(b));
  return r;
}

static __device__ __forceinline__ void gload_lds16(const unsigned short* g,
                                                   unsigned short* l) {
  __builtin_amdgcn_global_load_lds((const __attribute__((address_space(1))) void*)g,
                                   (__attribute__((address_space(3))) void*)l, 16, 0, 0);
}

// 4 weights [K,N] fp32 -> [N,K] bf16 in one launch
__global__ void wtrans4_kernel(const float* __restrict__ W0, const float* __restrict__ W1,
                               const float* __restrict__ W2, const float* __restrict__ W3,
                               unsigned short* __restrict__ T0, unsigned short* __restrict__ T1,
                               unsigned short* __restrict__ T2, unsigned short* __restrict__ T3) {
  const float* W = blockIdx.z == 0 ? W0 : (blockIdx.z == 1 ? W1 : (blockIdx.z == 2 ? W2 : W3));
  unsigned short* Wt = blockIdx.z == 0 ? T0 : (blockIdx.z == 1 ? T1 : (blockIdx.z == 2 ? T2 : T3));
  __shared__ float t[32][33];
  int n0 = blockIdx.x * 32, k0 = blockIdx.y * 32;
#pragma unroll
  for (int j = 0; j < 4; ++j)
    t[threadIdx.y + j * 8][threadIdx.x] =
        W[(size_t)(k0 + threadIdx.y + j * 8) * 1024 + n0 + threadIdx.x];
  __syncthreads();
#pragma unroll
  for (int j = 0; j < 4; ++j)
    Wt[(size_t)(n0 + threadIdx.y + j * 8) * 1024 + k0 + threadIdx.x] =
        f2bf(t[threadIdx.x][threadIdx.y + j * 8]);
}

// energy -> Mf (float 0/1) and Mbf (bf16 0/1)
__global__ void mask_kernel(const float* __restrict__ e, float* __restrict__ Mf,
                            unsigned short* __restrict__ Mbf, int n) {
  int i = blockIdx.x * blockDim.x + threadIdx.x;
  if (i < n) {
    float m = (fabsf(e[i]) > 0.1f) ? 1.0f : 0.0f;
    Mf[i] = m;
    Mbf[i] = f2bf(m);
  }
}

// ---------------- fused QKV GEMM v9 (measured best): raw-barrier pipeline ----------
// SWAP=1 (grid.z=2): z=0 -> Qh=(q_x@Wq+bq)*c2 [B,H,L,64]; z=1 -> Kh [B,H,S,64].
// SWAP=0 (grid.z=1): Vt=(v_x@Wv+bv)*Mf [B,H,64,S].
// B triple-buffered (staged 2 tiles ahead); A double-buffered via
// reg->cvtpk->ds_write (conv fused). Loads drained implicitly by writeA's
// register deps; in-loop barrier is raw s_barrier + lgkmcnt(0) only.
template <int SWAP>
__global__ __launch_bounds__(256, 4) void gemm_qkv_kernel(
    const float* __restrict__ Xq32, const float* __restrict__ Xk32,
    const float* __restrict__ Xv32, const unsigned short* __restrict__ Wtq,
    const unsigned short* __restrict__ Wtk, const unsigned short* __restrict__ Wtv,
    const float* __restrict__ bq, const float* __restrict__ bk, const float* __restrict__ bv,
    unsigned short* __restrict__ Qh, unsigned short* __restrict__ Kh,
    unsigned short* __restrict__ Vt, const float* __restrict__ Mf, float c2) {
  const int K = 1024;
  __shared__ unsigned short Al[2][128 * 32];
  __shared__ unsigned short Bl[3][128 * 32];
  const int z = SWAP ? blockIdx.z : 2;
  const float* X32 = SWAP ? (blockIdx.z == 0 ? Xq32 : Xk32) : Xv32;
  const unsigned short* Wt = SWAP ? (blockIdx.z == 0 ? Wtq : Wtk) : Wtv;
  const float* bias = SWAP ? (blockIdx.z == 0 ? bq : bk) : bv;
  const int m0 = blockIdx.x * 128, n0 = blockIdx.y * 128;
  const int tid = threadIdx.x, lane = tid & 63, wid = tid >> 6;
  const int wr = wid >> 1, wc = wid & 1;
  const int g = lane >> 4, lr = lane & 15;
  const f32x4 fz = {0.f, 0.f, 0.f, 0.f};
  f32x4 acc[4][4];
#pragma unroll
  for (int i = 0; i < 4; i++)
#pragma unroll
    for (int j = 0; j < 4; j++) acc[i][j] = fz;

  const int sr0 = tid >> 2;
  const int sr1 = (256 + tid) >> 2;
  const int chk = ((tid & 3) ^ ((tid >> 3) & 3)) * 8;   // swizzled source chunk (elems)
  const int offr = (g ^ ((lr >> 1) & 3)) * 8;           // swizzled read offset (shorts)
  const float* pA0 = X32 + (size_t)(m0 + sr0) * K + chk;
  const float* pA1 = X32 + (size_t)(m0 + sr1) * K + chk;

  float4 ra0, ra1, rb0, rb1;  // A-tile in flight (fp32)

  auto stageB = [&](int kk, int bi) {
    gload_lds16(Wt + (size_t)(n0 + sr0) * K + kk + chk, &Bl[bi][wid * 512]);
    gload_lds16(Wt + (size_t)(n0 + sr1) * K + kk + chk, &Bl[bi][2048 + wid * 512]);
  };
  auto loadA = [&](int kk) {
    ra0 = *(const float4*)(pA0 + kk);
    ra1 = *(const float4*)(pA0 + kk + 4);
    rb0 = *(const float4*)(pA1 + kk);
    rb1 = *(const float4*)(pA1 + kk + 4);
  };
  auto writeA = [&](int ai) {
    uint4 s0, s1;
    s0.x = cvtpk(ra0.x, ra0.y); s0.y = cvtpk(ra0.z, ra0.w);
    s0.z = cvtpk(ra1.x, ra1.y); s0.w = cvtpk(ra1.z, ra1.w);
    s1.x = cvtpk(rb0.x, rb0.y); s1.y = cvtpk(rb0.z, rb0.w);
    s1.z = cvtpk(rb1.x, rb1.y); s1.w = cvtpk(rb1.z, rb1.w);
    *(uint4*)(&Al[ai][tid * 8]) = s0;
    *(uint4*)(&Al[ai][2048 + tid * 8]) = s1;
  };

  // prologue: B tiles 0,1 staged; A tile 0 written; A tile 1 in regs
  loadA(0);
  stageB(0, 0);
  writeA(0);       // implicit wait on loadA(0)
  stageB(32, 1);
  loadA(32);
  __syncthreads();  // one full drain (prologue only)

  int ab = 0;                 // A buffer of current tile
  int b0 = 0, b1 = 1, b2 = 2; // B bufs: current / next / stage-target
  for (int t = 0; t < 32; ++t) {
    const int k0 = t * 32;
    if (t < 31) writeA(ab ^ 1);            // tile t+1 (regs loaded a full iter ago)
    if (t < 30) {
      stageB(k0 + 64, b2);                 // tile t+2 (read 2 barriers later)
      loadA(k0 + 64);                      // tile t+2 A regs
    }
    short8 a[4], b[4];
#pragma unroll
    for (int i = 0; i < 4; i++)
      a[i] = *(const short8*)(&Al[ab][(wr * 64 + i * 16 + lr) * 32 + offr]);
#pragma unroll
    for (int i = 0; i < 4; i++)
      b[i] = *(const short8*)(&Bl[b0][(wc * 64 + i * 16 + lr) * 32 + offr]);
#pragma unroll
    for (int i = 0; i < 4; i++)
#pragma unroll
      for (int j = 0; j < 4; j++) {
        if (SWAP)
          acc[i][j] = __builtin_amdgcn_mfma_f32_16x16x32_bf16(b[j], a[i], acc[i][j], 0, 0, 0);
        else
          acc[i][j] = __builtin_amdgcn_mfma_f32_16x16x32_bf16(a[i], b[j], acc[i][j], 0, 0, 0);
      }
    asm volatile("s_waitcnt lgkmcnt(0)" ::: "memory");  // ds_writes visible
    __builtin_amdgcn_s_barrier();                       // raw: no vmcnt drain
    __builtin_amdgcn_sched_barrier(0);                  // pin the boundary
    ab ^= 1;
    int tmp = b0; b0 = b1; b1 = b2; b2 = tmp;
  }

  if (SWAP) {
    const float scale = (z == 0) ? c2 : 1.0f;
    unsigned short* out = z == 0 ? Qh : Kh;
#pragma unroll
    for (int i = 0; i < 4; i++) {
      const int mrow = m0 + wr * 64 + i * 16 + lr;
      const int b_ = mrow >> 11, l = mrow & 2047;
#pragma unroll
      for (int j = 0; j < 4; j++) {
        const int ncol0 = n0 + wc * 64 + j * 16 + g * 4;
        const int h = ncol0 >> 6, dh = ncol0 & 63;
        const f32x4 bb = *(const f32x4*)(bias + ncol0);
        uint2 st;
        st.x = cvtpk((acc[i][j][0] + bb[0]) * scale, (acc[i][j][1] + bb[1]) * scale);
        st.y = cvtpk((acc[i][j][2] + bb[2]) * scale, (acc[i][j][3] + bb[3]) * scale);
        *(uint2*)(out + ((size_t)(b_ * 16 + h) * 2048 + l) * 64 + dh) = st;
      }
    }
  } else {
#pragma unroll
    for (int i = 0; i < 4; i++) {
      const int mrow0 = m0 + wr * 64 + i * 16 + g * 4;
      const int b_ = mrow0 >> 11, s = mrow0 & 2047;
      const f32x4 mf = *(const f32x4*)(Mf + mrow0);
#pragma unroll
      for (int j = 0; j < 4; j++) {
        const int ncol = n0 + wc * 64 + j * 16 + lr;
        const float bv_ = bias[ncol];
        const int h = ncol >> 6, d = ncol & 63;
        uint2 pk;
        pk.x = cvtpk((acc[i][j][0] + bv_) * mf[0], (acc[i][j][1] + bv_) * mf[1]);
        pk.y = cvtpk((acc[i][j][2] + bv_) * mf[2], (acc[i][j][3] + bv_) * mf[3]);
        *(uint2*)(Vt + ((size_t)(b_ * 16 + h) * 64 + d) * 2048 + s) = pk;
      }
    }
  }
}

// ---------------- output GEMM v5 (fp32 out, swapped, swizzled) ----------------
__global__ __launch_bounds__(256, 4) void gemm_out_kernel(
    const unsigned short* __restrict__ X, const unsigned short* __restrict__ Wt,
    const float* __restrict__ bias, float* __restrict__ out) {
  const int K = 1024;
  __shared__ unsigned short Al[2][128 * 32];
  __shared__ unsigned short Bl[2][128 * 32];
  const int m0 = blockIdx.x * 128, n0 = blockIdx.y * 128;
  const int tid = threadIdx.x, lane = tid & 63, wid = tid >> 6;
  const int wr = wid >> 1, wc = wid & 1;
  const int g = lane >> 4, lr = lane & 15;
  const f32x4 fz = {0.f, 0.f, 0.f, 0.f};
  f32x4 acc[4][4];
#pragma unroll
  for (int i = 0; i < 4; i++)
#pragma unroll
    for (int j = 0; j < 4; j++) acc[i][j] = fz;

  const int sr0 = tid >> 2;
  const int sr1 = (256 + tid) >> 2;
  const int sc0s = ((tid & 3) ^ ((tid >> 3) & 3)) * 8;
  const int offr = (g ^ ((lr >> 1) & 3)) * 8;

  auto stage = [&](int kk, int buf) {
    gload_lds16(X + (size_t)(m0 + sr0) * K + kk + sc0s, &Al[buf][wid * 512]);
    gload_lds16(X + (size_t)(m0 + sr1) * K + kk + sc0s, &Al[buf][2048 + wid * 512]);
    gload_lds16(Wt + (size_t)(n0 + sr0) * K + kk + sc0s, &Bl[buf][wid * 512]);
    gload_lds16(Wt + (size_t)(n0 + sr1) * K + kk + sc0s, &Bl[buf][2048 + wid * 512]);
  };

  stage(0, 0);
  __syncthreads();

  int buf = 0;
  for (int k0 = 0; k0 < K; k0 += 32) {
    if (k0 < K - 32) stage(k0 + 32, buf ^ 1);
    short8 a[4], b[4];
#pragma unroll
    for (int i = 0; i < 4; i++)
      a[i] = *(const short8*)(&Al[buf][(wr * 64 + i * 16 + lr) * 32 + offr]);
#pragma unroll
    for (int i = 0; i < 4; i++)
      b[i] = *(const short8*)(&Bl[buf][(wc * 64 + i * 16 + lr) * 32 + offr]);
#pragma unroll
    for (int i = 0; i < 4; i++)
#pragma unroll
      for (int j = 0; j < 4; j++)
        acc[i][j] = __builtin_amdgcn_mfma_f32_16x16x32_bf16(b[j], a[i], acc[i][j], 0, 0, 0);
    __syncthreads();
    buf ^= 1;
  }

#pragma unroll
  for (int i = 0; i < 4; i++) {
    const int mrow = m0 + wr * 64 + i * 16 + lr;
#pragma unroll
    for (int j = 0; j < 4; j++) {
      const int ncol0 = n0 + wc * 64 + j * 16 + g * 4;
      const f32x4 bb = *(const f32x4*)(bias + ncol0);
      f32x4 st = acc[i][j] + bb;
      *(f32x4*)(out + (size_t)mrow * 1024 + ncol0) = st;
    }
  }
}

// ---------------- flash attention v12 ----------------
__global__ __launch_bounds__(256, 4) void attn_kernel(
    const unsigned short* __restrict__ Qh, const unsigned short* __restrict__ Kh,
    const unsigned short* __restrict__ Vt, const unsigned short* __restrict__ Mbf,
    unsigned short* __restrict__ AO) {
  const int S = 2048;
  __shared__ unsigned short Lds[2][8192];
  int bx = blockIdx.x;
  int lid = (bx & 7) * 128 + (bx >> 3);
  const int bh = lid >> 4, qbb = lid & 15;
  const int b_ = bh >> 4, h = bh & 15;
  const unsigned short* Qp = Qh + (size_t)bh * S * 64;
  const unsigned short* Kp = Kh + (size_t)bh * S * 64;
  const unsigned short* Vp = Vt + (size_t)bh * 64 * S;
  const unsigned short* Mp = Mbf + b_ * S;
  const int tid = threadIdx.x, lane = tid & 63, wid = tid >> 6;
  const int g = lane >> 4, lr = lane & 15;
  const int qbase = qbb * 128 + wid * 32;
  const f32x4 fz = {0.f, 0.f, 0.f, 0.f};

  const int srow = (lane >> 3);
  const int schk = (lane & 7) ^ srow;
  const int kr0 = wid * 16 + srow, kr1 = wid * 16 + 8 + srow;
  const int pir0 = (kr0 & 32) | ((kr0 & 12) << 1) | ((kr0 & 16) >> 2) | (kr0 & 3);
  const int pir1 = (kr1 & 32) | ((kr1 & 12) << 1) | ((kr1 & 16) >> 2) | (kr1 & 3);
  const unsigned short* gK0 = Kp + (size_t)pir0 * 64 + schk * 8;
  const unsigned short* gK1 = Kp + (size_t)pir1 * 64 + schk * 8;
  const unsigned short* gV0 = Vp + (size_t)kr0 * S + schk * 8;
  const unsigned short* gV1 = Vp + (size_t)kr1 * S + schk * 8;

  const int s7 = lr & 7;
  const int off0 = ((g ^ s7) * 8);
  const int off1 = (((4 + g) ^ s7) * 8);

  short8 qf[2][2];
#pragma unroll
  for (int qt = 0; qt < 2; qt++)
#pragma unroll
    for (int kh = 0; kh < 2; kh++)
      qf[qt][kh] = *(const short8*)(Qp + (size_t)(qbase + qt * 16 + lr) * 64 + kh * 32 + g * 8);

  f32x4 o[2][4];
  f32x4 psA[2];
#pragma unroll
  for (int qt = 0; qt < 2; qt++) {
    psA[qt] = fz;
#pragma unroll
    for (int t = 0; t < 4; t++) o[qt][t] = fz;
  }

  auto stage = [&](int s0, int buf) {
    gload_lds16(gK0 + (size_t)s0 * 64, &Lds[buf][wid * 1024]);
    gload_lds16(gK1 + (size_t)s0 * 64, &Lds[buf][wid * 1024 + 512]);
    gload_lds16(gV0 + s0, &Lds[buf][4096 + wid * 1024]);
    gload_lds16(gV1 + s0, &Lds[buf][4096 + wid * 1024 + 512]);
  };

  stage(0, 0);
  __syncthreads();

  int cur = 0;
  for (int t = 0; t < 32; ++t) {
    const int s0 = t * 64;
    if (t < 31) stage(s0 + 64, cur ^ 1);
    const unsigned short* Kb = &Lds[cur][lr * 64];
    const unsigned short* Vb = &Lds[cur][4096 + lr * 64];

    short8 kf[4][2];
#pragma unroll
    for (int st = 0; st < 4; st++) {
      kf[st][0] = *(const short8*)(Kb + st * 1024 + off0);
      kf[st][1] = *(const short8*)(Kb + st * 1024 + off1);
    }
    short8 mk0 = *(const short8*)(Mp + s0 + g * 8);
    short8 mk1 = *(const short8*)(Mp + s0 + 32 + g * 8);

    union { unsigned u[8]; short8 s8[2]; } pk[2];
    __builtin_amdgcn_s_setprio(1);
#pragma unroll
    for (int qt = 0; qt < 2; qt++) {
#pragma unroll
      for (int st = 0; st < 4; st++) {
        f32x4 a0 = __builtin_amdgcn_mfma_f32_16x16x32_bf16(kf[st][0], qf[qt][0], fz, 0, 0, 0);
        f32x4 s = __builtin_amdgcn_mfma_f32_16x16x32_bf16(kf[st][1], qf[qt][1], a0, 0, 0, 0);
        f32x4 p;
#pragma unroll
        for (int e = 0; e < 4; e++) p[e] = __builtin_amdgcn_exp2f(s[e]);
        pk[qt].u[st * 2] = cvtpk(p[0], p[1]);
        pk[qt].u[st * 2 + 1] = cvtpk(p[2], p[3]);
      }
      psA[qt] = __builtin_amdgcn_mfma_f32_16x16x32_bf16(mk0, pk[qt].s8[0], psA[qt], 0, 0, 0);
      psA[qt] = __builtin_amdgcn_mfma_f32_16x16x32_bf16(mk1, pk[qt].s8[1], psA[qt], 0, 0, 0);
    }
    __builtin_amdgcn_s_setprio(0);

#pragma unroll
    for (int tt = 0; tt < 4; tt++) {
      short8 v0 = *(const short8*)(Vb + tt * 1024 + off0);
      short8 v1 = *(const short8*)(Vb + tt * 1024 + off1);
      __builtin_amdgcn_s_setprio(1);
#pragma unroll
      for (int qt = 0; qt < 2; qt++) {
        o[qt][tt] = __builtin_amdgcn_mfma_f32_16x16x32_bf16(v0, pk[qt].s8[0], o[qt][tt], 0, 0, 0);
        o[qt][tt] = __builtin_amdgcn_mfma_f32_16x16x32_bf16(v1, pk[qt].s8[1], o[qt][tt], 0, 0, 0);
      }
      __builtin_amdgcn_s_setprio(0);
    }
    __syncthreads();
    cur ^= 1;
  }

#pragma unroll
  for (int qt = 0; qt < 2; qt++) {
    float l = psA[qt][0];
    float inv = l > 0.f ? 1.f / l : 0.f;
    size_t row = (size_t)b_ * 2048 + qbase + qt * 16 + lr;
#pragma unroll
    for (int tt = 0; tt < 4; tt++) {
      uint2 wv;
      wv.x = cvtpk(o[qt][tt][0] * inv, o[qt][tt][1] * inv);
      wv.y = cvtpk(o[qt][tt][2] * inv, o[qt][tt][3] * inv);
      *(uint2*)(AO + row * 1024 + h * 64 + tt * 16 + g * 4) = wv;
    }
  }
}

// ---------------- launch ----------------
extern "C" void kernel_launch(void* const* d_in, const int* in_sizes, int n_in,
                              void* d_out, int out_size, void* d_ws, size_t ws_size,
                              hipStream_t stream) {
  const float* q_x = (const float*)d_in[0];
  const float* k_x = (const float*)d_in[1];
  const float* v_x = (const float*)d_in[2];
  const float* energy = (const float*)d_in[3];
  const float* Wq = (const float*)d_in[4];
  const float* bq = (const float*)d_in[5];
  const float* Wk = (const float*)d_in[6];
  const float* bk = (const float*)d_in[7];
  const float* Wv = (const float*)d_in[8];
  const float* bv = (const float*)d_in[9];
  const float* Wo = (const float*)d_in[10];
  const float* bo = (const float*)d_in[11];

  char* w = (char*)d_ws;
  auto take = [&](size_t bytes) {
    char* p = w;
    w += (bytes + 255) & ~(size_t)255;
    return p;
  };
  const size_t XB = (size_t)8192 * 1024 * 2;
  unsigned short* Wtq = (unsigned short*)take((size_t)1024 * 1024 * 2);
  unsigned short* Wtk = (unsigned short*)take((size_t)1024 * 1024 * 2);
  unsigned short* Wtv = (unsigned short*)take((size_t)1024 * 1024 * 2);
  unsigned short* Wto = (unsigned short*)take((size_t)1024 * 1024 * 2);
  float* Mf = (float*)take((size_t)8192 * 4);
  unsigned short* Mbf = (unsigned short*)take((size_t)8192 * 2);
  unsigned short* Qh = (unsigned short*)take(XB);
  unsigned short* Kh = (unsigned short*)take(XB);
  unsigned short* Vt = (unsigned short*)take(XB);
  unsigned short* AO = (unsigned short*)take(XB);

  const float c2 = 0.18033688011f;  // log2(e)/sqrt(64)
  wtrans4_kernel<<<dim3(32, 32, 4), dim3(32, 8), 0, stream>>>(Wq, Wk, Wv, Wo, Wtq, Wtk, Wtv, Wto);
  mask_kernel<<<32, 256, 0, stream>>>(energy, Mf, Mbf, 8192);

  gemm_qkv_kernel<1><<<dim3(64, 8, 2), 256, 0, stream>>>(q_x, k_x, v_x, Wtq, Wtk, Wtv,
                                                         bq, bk, bv, Qh, Kh, Vt, Mf, c2);
  gemm_qkv_kernel<0><<<dim3(64, 8, 1), 256, 0, stream>>>(q_x, k_x, v_x, Wtq, Wtk, Wtv,
                                                         bq, bk, bv, Qh, Kh, Vt, Mf, c2);
  attn_kernel<<<1024, 256, 0, stream>>>(Qh, Kh, Vt, Mbf, AO);
  gemm_out_kernel<<<dim3(64, 8), 256, 0, stream>>>(AO, Wto, bo, (float*)d_out);
}